// Round 8
// baseline (488.102 us; speedup 1.0000x reference)
//
#include <hip/hip_runtime.h>

#define NUM_USER 100000
#define NUM_ITEM 50000
#define NUM_NODES 150000
#define FEAT_DIM 512
#define DLAT 64
#define HID 256

// bucketed CSR build
#define BSHIFT 9
#define BWIDTH 512                       // nodes per bucket
#define NBUCK 293                        // ceil(150000/512)
#define CPAIR 6144                       // pairs per bucket_scatter2 block (emits 12288 entries)

typedef float f32x4 __attribute__((ext_vector_type(4)));
typedef __bf16 bf16x8 __attribute__((ext_vector_type(8)));
typedef unsigned short ushort8v __attribute__((ext_vector_type(8)));

union BF8 { ushort8v u; bf16x8 b; };

__device__ inline unsigned short f2bf_rne(float f) {
    unsigned u = __float_as_uint(f);
    u += 0x7FFFu + ((u >> 16) & 1u);
    return (unsigned short)(u >> 16);
}

__device__ inline float bf_lo(unsigned v) { return __uint_as_float(v << 16); }
__device__ inline float bf_hi(unsigned v) { return __uint_as_float(v & 0xffff0000u); }

// ---------------- pass A: bucket histogram over undirected pairs ----------------
__global__ void bucket_hist2(const int* __restrict__ usrc, const int* __restrict__ idst,
                             int* __restrict__ bhist, int npair) {
    __shared__ int h[NBUCK];
    for (int i = threadIdx.x; i < NBUCK; i += blockDim.x) h[i] = 0;
    __syncthreads();
    const int stride = gridDim.x * blockDim.x;
    for (int i = blockIdx.x * blockDim.x + threadIdx.x; i < npair; i += stride) {
        atomicAdd(&h[usrc[i] >> BSHIFT], 1);
        atomicAdd(&h[idst[i] >> BSHIFT], 1);
    }
    __syncthreads();
    for (int i = threadIdx.x; i < NBUCK; i += blockDim.x)
        if (h[i]) atomicAdd(&bhist[i], h[i]);
}

// ---------------- pass A2: exclusive scan of bucket histogram ----------------
__global__ void bucket_scan(const int* __restrict__ bhist, int* __restrict__ bbase) {
    __shared__ int s[512];
    const int t = threadIdx.x;
    const int v = (t < NBUCK) ? bhist[t] : 0;
    s[t] = v;
    __syncthreads();
    for (int off = 1; off < 512; off <<= 1) {
        int add = (t >= off) ? s[t - off] : 0;
        __syncthreads();
        s[t] += add;
        __syncthreads();
    }
    if (t < NBUCK) bbase[t] = s[t] - v;  // exclusive
}

// ---------------- pass B: LDS-staged scatter into bucket-grouped packed pairs ----------------
__launch_bounds__(256)
__global__ void bucket_scatter2(const int* __restrict__ usrc, const int* __restrict__ idst,
                                const int* __restrict__ bbase, int* __restrict__ gfill,
                                unsigned* __restrict__ pairs, int npair) {
    __shared__ unsigned stage[2 * CPAIR];   // 48 KB
    __shared__ int h[NBUCK];
    __shared__ int loff[NBUCK];
    __shared__ int gbase[NBUCK];
    __shared__ int offl[512];

    const int t = threadIdx.x;
    for (int i = t; i < NBUCK; i += 256) h[i] = 0;
    __syncthreads();

    const int p0 = blockIdx.x * CPAIR;
    const int p1 = min(p0 + CPAIR, npair);

    for (int j = p0 + t; j < p1; j += 256) {
        atomicAdd(&h[usrc[j] >> BSHIFT], 1);
        atomicAdd(&h[idst[j] >> BSHIFT], 1);
    }
    __syncthreads();

    const int v0 = h[t];
    const int v1 = (t + 256 < NBUCK) ? h[t + 256] : 0;
    offl[t] = v0; offl[t + 256] = v1;
    __syncthreads();
    for (int off = 1; off < 512; off <<= 1) {
        int a0 = (t >= off) ? offl[t - off] : 0;
        int a1 = offl[t + 256 - off];
        __syncthreads();
        offl[t] += a0;
        offl[t + 256] += a1;
        __syncthreads();
    }
    loff[t] = offl[t] - v0;
    if (t + 256 < NBUCK) loff[t + 256] = offl[t + 256] - v1;
    __syncthreads();

    for (int i = t; i < NBUCK; i += 256) {
        int c = h[i];
        gbase[i] = c ? (bbase[i] + atomicAdd(&gfill[i], c)) : 0;
    }
    __syncthreads();
    for (int i = t; i < NBUCK; i += 256) h[i] = 0;
    __syncthreads();

    for (int j = p0 + t; j < p1; j += 256) {
        int u = usrc[j], v = idst[j];
        int bu = u >> BSHIFT, bv = v >> BSHIFT;
        int pu = atomicAdd(&h[bu], 1);
        stage[loff[bu] + pu] = ((unsigned)(u & (BWIDTH - 1)) << 18) | (unsigned)v;
        int pv = atomicAdd(&h[bv], 1);
        stage[loff[bv] + pv] = ((unsigned)(v & (BWIDTH - 1)) << 18) | (unsigned)u;
    }
    __syncthreads();

    const int wv = t >> 6, ln = t & 63;
    for (int b = wv; b < NBUCK; b += 4) {
        const int len = h[b];
        const int lo  = loff[b];
        unsigned* gp = pairs + gbase[b];
        for (int k = ln; k < len; k += 64) gp[k] = stage[lo + k];
    }
}

// ---------------- pass CD: per-bucket degree count + rowptr/dinv + CSR fill ----------------
__launch_bounds__(256)
__global__ void csr_build(const int* __restrict__ bhist, const int* __restrict__ bbase,
                          const unsigned* __restrict__ pairs,
                          int* __restrict__ rowptr, float* __restrict__ dinv,
                          int* __restrict__ col) {
    __shared__ int degl[BWIDTH];
    __shared__ int offl[BWIDTH];
    const int b = blockIdx.x;
    const int t = threadIdx.x;
    const int node0 = b << BSHIFT;
    const int e0 = bbase[b];
    const int ecnt = bhist[b];

    degl[t] = 0; degl[t + 256] = 0;
    __syncthreads();
    for (int i = t; i < ecnt; i += 256)
        atomicAdd(&degl[pairs[e0 + i] >> 18], 1);
    __syncthreads();

    const int v0 = degl[t], v1 = degl[t + 256];
    offl[t] = v0; offl[t + 256] = v1;
    __syncthreads();
    for (int off = 1; off < 512; off <<= 1) {
        int a0 = (t >= off) ? offl[t - off] : 0;
        int a1 = offl[t + 256 - off];
        __syncthreads();
        offl[t] += a0;
        offl[t + 256] += a1;
        __syncthreads();
    }
    const int excl0 = offl[t] - v0;
    const int excl1 = offl[t + 256] - v1;

    const int n0 = node0 + t, n1 = node0 + t + 256;
    if (n0 < NUM_NODES) {
        rowptr[n0] = e0 + excl0;
        dinv[n0] = v0 > 0 ? rsqrtf((float)v0) : 0.0f;
    }
    if (n1 < NUM_NODES) {
        rowptr[n1] = e0 + excl1;
        dinv[n1] = v1 > 0 ? rsqrtf((float)v1) : 0.0f;
    }
    if (b == NBUCK - 1 && t == 0) rowptr[NUM_NODES] = e0 + ecnt;
    __syncthreads();

    offl[t] = excl0; offl[t + 256] = excl1;
    degl[t] = 0;     degl[t + 256] = 0;
    __syncthreads();
    for (int i = t; i < ecnt; i += 256) {
        unsigned p = pairs[e0 + i];
        int sl = p >> 18;
        int d  = (int)(p & 0x3FFFFu);
        int pos = atomicAdd(&degl[sl], 1);
        col[e0 + offl[sl] + pos] = d;
    }
}

// ---------------- weight conversion (transpose to bf16) ----------------
__global__ void convert_weights(const float* __restrict__ W1, const float* __restrict__ W2,
                                unsigned short* __restrict__ w1t, unsigned short* __restrict__ w2t) {
    int idx = blockIdx.x * blockDim.x + threadIdx.x;
    if (idx < FEAT_DIM * HID) {
        int k = idx / HID, n = idx % HID;
        w1t[(size_t)n * FEAT_DIM + k] = f2bf_rne(W1[idx]);
    } else {
        int j = idx - FEAT_DIM * HID;
        if (j < HID * DLAT) {
            int k = j / DLAT, n = j % DLAT;
            w2t[(size_t)n * HID + k] = f2bf_rne(W2[j]);
        }
    }
}

// ---------------- fused item MLP: GEMM1 (128x256, K=512) + GEMM2 (128x64, K=256) ----------------
// sH stored with chunk-swizzle: ushort idx = row*256 + ((chunk)^(row&7))*8 + within,
// chunk = col>>3, within = col&7. Kills 512B-stride bank conflicts on gemm2 A-reads.
__launch_bounds__(512, 4)
__global__ void mlp_fused(const float* __restrict__ feats,
                          const unsigned short* __restrict__ w1t,
                          const unsigned short* __restrict__ w2t,
                          const float* __restrict__ b1,
                          const float* __restrict__ b2,
                          const float* __restrict__ dinv,
                          float* __restrict__ out,
                          unsigned short* __restrict__ xs) {
    __shared__ __align__(16) unsigned char smem[65536];
    unsigned short* sA = (unsigned short*)smem;
    unsigned short* sB = (unsigned short*)(smem + 8192);
    unsigned short* sH = (unsigned short*)smem;

    const int t    = threadIdx.x;
    const int lane = t & 63;
    const int w    = t >> 6;        // 0..7
    const int wr   = w >> 2;        // 0..1
    const int wc   = w & 3;         // 0..3
    const int l15  = lane & 15;
    const int l4   = lane >> 4;
    const int item0 = blockIdx.x * 128;

    const int a_k4  = t >> 7;
    const int a_row = t & 127;
    const int a_rowg = min(item0 + a_row, NUM_ITEM - 1);
    const float* a_src = feats + (size_t)a_rowg * FEAT_DIM + a_k4 * 8;
    unsigned short* a_dst = sA + a_k4 * 1024 + a_row * 8;

    const int b_col = t & 255;
    const int b_kq  = (t >> 8) * 2;
    const unsigned short* b_src = w1t + (size_t)b_col * FEAT_DIM + b_kq * 8;
    unsigned short* b_dst = sB + b_kq * 2048 + b_col * 8;

    f32x4 acc[4][4];
    #pragma unroll
    for (int i = 0; i < 4; ++i)
        #pragma unroll
        for (int j = 0; j < 4; ++j) acc[i][j] = (f32x4)0.0f;

    for (int kk = 0; kk < 16; ++kk) {
        const int kbase = kk * 32;
        float4 f0 = *reinterpret_cast<const float4*>(a_src + kbase);
        float4 f1 = *reinterpret_cast<const float4*>(a_src + kbase + 4);
        BF8 ta;
        ta.u[0] = f2bf_rne(f0.x); ta.u[1] = f2bf_rne(f0.y);
        ta.u[2] = f2bf_rne(f0.z); ta.u[3] = f2bf_rne(f0.w);
        ta.u[4] = f2bf_rne(f1.x); ta.u[5] = f2bf_rne(f1.y);
        ta.u[6] = f2bf_rne(f1.z); ta.u[7] = f2bf_rne(f1.w);
        *reinterpret_cast<ushort8v*>(a_dst) = ta.u;
        ushort8v bv0 = *reinterpret_cast<const ushort8v*>(b_src + kbase);
        ushort8v bv1 = *reinterpret_cast<const ushort8v*>(b_src + kbase + 8);
        *reinterpret_cast<ushort8v*>(b_dst)        = bv0;
        *reinterpret_cast<ushort8v*>(b_dst + 2048) = bv1;
        __syncthreads();

        BF8 af[4];
        #pragma unroll
        for (int rf = 0; rf < 4; ++rf)
            af[rf].u = *reinterpret_cast<const ushort8v*>(sA + l4 * 1024 + (wr * 64 + rf * 16 + l15) * 8);
        #pragma unroll
        for (int cf = 0; cf < 4; ++cf) {
            BF8 bf;
            bf.u = *reinterpret_cast<const ushort8v*>(sB + l4 * 2048 + (wc * 64 + cf * 16 + l15) * 8);
            #pragma unroll
            for (int rf = 0; rf < 4; ++rf)
                acc[rf][cf] = __builtin_amdgcn_mfma_f32_16x16x32_bf16(af[rf].b, bf.b, acc[rf][cf], 0, 0, 0);
        }
        __syncthreads();
    }

    // epilogue 1: bias + leaky -> swizzled sH
    float bias[4];
    #pragma unroll
    for (int cf = 0; cf < 4; ++cf) bias[cf] = b1[wc * 64 + cf * 16 + l15];

    #pragma unroll
    for (int rf = 0; rf < 4; ++rf) {
        #pragma unroll
        for (int cf = 0; cf < 4; ++cf) {
            const int colc = wc * 64 + cf * 16 + l15;
            const int chunk = colc >> 3, within = colc & 7;
            #pragma unroll
            for (int r = 0; r < 4; ++r) {
                const int row = wr * 64 + rf * 16 + l4 * 4 + r;
                float h = acc[rf][cf][r] + bias[cf];
                h = h > 0.0f ? h : 0.01f * h;
                sH[row * 256 + ((chunk ^ (row & 7)) << 3) + within] = f2bf_rne(h);
            }
        }
    }
    __syncthreads();

    // GEMM2 in-block: rows w*16..w*16+15 (wave w), cols 0..63, K=256 from sH
    f32x4 acc2[4];
    #pragma unroll
    for (int j = 0; j < 4; ++j) acc2[j] = (f32x4)0.0f;

    const int arow = w * 16 + l15;
    const int rswz = arow & 7;
    for (int kk = 0; kk < 8; ++kk) {
        const int chunk = kk * 4 + l4;          // k = chunk*8
        BF8 ta;
        ta.u = *reinterpret_cast<const ushort8v*>(sH + arow * 256 + ((chunk ^ rswz) << 3));
        const int kbase = kk * 32 + l4 * 8;
        #pragma unroll
        for (int cf = 0; cf < 4; ++cf) {
            BF8 tb;
            tb.u = *reinterpret_cast<const ushort8v*>(w2t + (size_t)(cf * 16 + l15) * HID + kbase);
            acc2[cf] = __builtin_amdgcn_mfma_f32_16x16x32_bf16(ta.b, tb.b, acc2[cf], 0, 0, 0);
        }
    }

    #pragma unroll
    for (int cf = 0; cf < 4; ++cf) {
        const int colc = cf * 16 + l15;
        const float bias2 = b2[colc];
        #pragma unroll
        for (int r = 0; r < 4; ++r) {
            const int item = item0 + w * 16 + l4 * 4 + r;
            if (item < NUM_ITEM) {
                const int node = NUM_USER + item;
                float v = acc2[cf][r] + bias2;
                out[(size_t)node * DLAT + colc] = v;
                xs [(size_t)node * DLAT + colc] = f2bf_rne(v * dinv[node]);
            }
        }
    }
}

// ---------------- user init: out = pref, xs = bf16(pref * dinv) ----------------
__global__ void pref_init(const float* __restrict__ pref, const float* __restrict__ dinv,
                          float* __restrict__ out, unsigned short* __restrict__ xs, int n4) {
    int i = blockIdx.x * blockDim.x + threadIdx.x;
    if (i < n4) {
        float4 v = reinterpret_cast<const float4*>(pref)[i];
        float di = dinv[i >> 4];
        reinterpret_cast<float4*>(out)[i] = v;
        uint2 p;
        p.x = (unsigned)f2bf_rne(v.x * di) | ((unsigned)f2bf_rne(v.y * di) << 16);
        p.y = (unsigned)f2bf_rne(v.z * di) | ((unsigned)f2bf_rne(v.w * di) << 16);
        *reinterpret_cast<uint2*>(xs + (size_t)i * 4) = p;
    }
}

// ---------------- CSR gather hop: direct broadcast col loads, 32-row deep ----------------
// lane = (g, r16): group g in [0,4) handles rows j with (j-base)%4 == g;
// 16 lanes/group cover the 128B bf16 row (8B per lane).
__launch_bounds__(256)
__global__ void hop_csr(const int* __restrict__ rowptr, const int* __restrict__ col,
                        const float* __restrict__ dinv, const unsigned short* __restrict__ xs,
                        float* __restrict__ out, unsigned short* __restrict__ xs_next,
                        int is_final, int n) {
    const int wave = (blockIdx.x * blockDim.x + threadIdx.x) >> 6;
    const int lane = threadIdx.x & 63;
    if (wave >= n) return;
    const int r0  = rowptr[wave];
    const int r1  = rowptr[wave + 1];
    const int g   = lane >> 4;
    const int r16 = lane & 15;
    const char* xsb = (const char*)xs + r16 * 8;

    float s0 = 0.0f, s1 = 0.0f, s2 = 0.0f, s3 = 0.0f;

    int base = r0;
    // 32 rows per iter: 8 broadcast col loads + 8 independent row loads
    for (; base + 32 <= r1; base += 32) {
        int c0 = col[base + g];
        int c1 = col[base + 4 + g];
        int c2 = col[base + 8 + g];
        int c3 = col[base + 12 + g];
        int c4 = col[base + 16 + g];
        int c5 = col[base + 20 + g];
        int c6 = col[base + 24 + g];
        int c7 = col[base + 28 + g];
        uint2 v0 = *reinterpret_cast<const uint2*>(xsb + (size_t)c0 * 128);
        uint2 v1 = *reinterpret_cast<const uint2*>(xsb + (size_t)c1 * 128);
        uint2 v2 = *reinterpret_cast<const uint2*>(xsb + (size_t)c2 * 128);
        uint2 v3 = *reinterpret_cast<const uint2*>(xsb + (size_t)c3 * 128);
        uint2 v4 = *reinterpret_cast<const uint2*>(xsb + (size_t)c4 * 128);
        uint2 v5 = *reinterpret_cast<const uint2*>(xsb + (size_t)c5 * 128);
        uint2 v6 = *reinterpret_cast<const uint2*>(xsb + (size_t)c6 * 128);
        uint2 v7 = *reinterpret_cast<const uint2*>(xsb + (size_t)c7 * 128);
        s0 += bf_lo(v0.x); s1 += bf_hi(v0.x); s2 += bf_lo(v0.y); s3 += bf_hi(v0.y);
        s0 += bf_lo(v1.x); s1 += bf_hi(v1.x); s2 += bf_lo(v1.y); s3 += bf_hi(v1.y);
        s0 += bf_lo(v2.x); s1 += bf_hi(v2.x); s2 += bf_lo(v2.y); s3 += bf_hi(v2.y);
        s0 += bf_lo(v3.x); s1 += bf_hi(v3.x); s2 += bf_lo(v3.y); s3 += bf_hi(v3.y);
        s0 += bf_lo(v4.x); s1 += bf_hi(v4.x); s2 += bf_lo(v4.y); s3 += bf_hi(v4.y);
        s0 += bf_lo(v5.x); s1 += bf_hi(v5.x); s2 += bf_lo(v5.y); s3 += bf_hi(v5.y);
        s0 += bf_lo(v6.x); s1 += bf_hi(v6.x); s2 += bf_lo(v6.y); s3 += bf_hi(v6.y);
        s0 += bf_lo(v7.x); s1 += bf_hi(v7.x); s2 += bf_lo(v7.y); s3 += bf_hi(v7.y);
    }
    // 16 rows per iter
    for (; base + 16 <= r1; base += 16) {
        int c0 = col[base + g];
        int c1 = col[base + 4 + g];
        int c2 = col[base + 8 + g];
        int c3 = col[base + 12 + g];
        uint2 v0 = *reinterpret_cast<const uint2*>(xsb + (size_t)c0 * 128);
        uint2 v1 = *reinterpret_cast<const uint2*>(xsb + (size_t)c1 * 128);
        uint2 v2 = *reinterpret_cast<const uint2*>(xsb + (size_t)c2 * 128);
        uint2 v3 = *reinterpret_cast<const uint2*>(xsb + (size_t)c3 * 128);
        s0 += bf_lo(v0.x); s1 += bf_hi(v0.x); s2 += bf_lo(v0.y); s3 += bf_hi(v0.y);
        s0 += bf_lo(v1.x); s1 += bf_hi(v1.x); s2 += bf_lo(v1.y); s3 += bf_hi(v1.y);
        s0 += bf_lo(v2.x); s1 += bf_hi(v2.x); s2 += bf_lo(v2.y); s3 += bf_hi(v2.y);
        s0 += bf_lo(v3.x); s1 += bf_hi(v3.x); s2 += bf_lo(v3.y); s3 += bf_hi(v3.y);
    }
    // remainder: group g takes rows base+g, base+g+4, ...
    for (int jj = base + g; jj < r1; jj += 4) {
        int c = col[jj];
        uint2 v = *reinterpret_cast<const uint2*>(xsb + (size_t)c * 128);
        s0 += bf_lo(v.x); s1 += bf_hi(v.x); s2 += bf_lo(v.y); s3 += bf_hi(v.y);
    }

    // reduce across the 4 groups (lanes with same r16)
    s0 += __shfl_xor(s0, 16); s0 += __shfl_xor(s0, 32);
    s1 += __shfl_xor(s1, 16); s1 += __shfl_xor(s1, 32);
    s2 += __shfl_xor(s2, 16); s2 += __shfl_xor(s2, 32);
    s3 += __shfl_xor(s3, 16); s3 += __shfl_xor(s3, 32);

    if (g == 0) {
        float di = dinv[wave];
        float y0 = di * s0, y1 = di * s1, y2 = di * s2, y3 = di * s3;
        size_t o = (size_t)wave * DLAT + 4 * r16;
        float4 prev = *reinterpret_cast<const float4*>(out + o);
        if (is_final) {
            float4 wv;
            wv.x = (prev.x + y0) * (1.0f / 3.0f);
            wv.y = (prev.y + y1) * (1.0f / 3.0f);
            wv.z = (prev.z + y2) * (1.0f / 3.0f);
            wv.w = (prev.w + y3) * (1.0f / 3.0f);
            *reinterpret_cast<float4*>(out + o) = wv;
        } else {
            float4 wv;
            wv.x = prev.x + y0;
            wv.y = prev.y + y1;
            wv.z = prev.z + y2;
            wv.w = prev.w + y3;
            *reinterpret_cast<float4*>(out + o) = wv;
            uint2 p;
            p.x = (unsigned)f2bf_rne(di * y0) | ((unsigned)f2bf_rne(di * y1) << 16);
            p.y = (unsigned)f2bf_rne(di * y2) | ((unsigned)f2bf_rne(di * y3) << 16);
            *reinterpret_cast<uint2*>(xs_next + o) = p;
        }
    }
}

extern "C" void kernel_launch(void* const* d_in, const int* in_sizes, int n_in,
                              void* d_out, int out_size, void* d_ws, size_t ws_size,
                              hipStream_t stream) {
    const float* feats = (const float*)d_in[0];
    const int*   eidx  = (const int*)d_in[1];
    const float* pref  = (const float*)d_in[2];
    const float* W1    = (const float*)d_in[3];
    const float* b1    = (const float*)d_in[4];
    const float* W2    = (const float*)d_in[5];
    const float* b2    = (const float*)d_in[6];

    const int E = in_sizes[1] / 2;       // directed edges
    const int npair = E / 2;             // undirected pairs; row0 = [src_u | dst_i]
    const int* usrc = eidx;
    const int* idst = eidx + npair;

    char* ws = (char*)d_ws;
    size_t off = 0;
    auto alloc = [&](size_t bytes) -> void* {
        void* p = ws + off;
        off += (bytes + 255) & ~(size_t)255;
        return p;
    };
    const size_t xsbytes = (size_t)NUM_NODES * DLAT * sizeof(unsigned short);
    unsigned short* xsA = (unsigned short*)alloc(xsbytes);
    unsigned short* xsB = (unsigned short*)alloc(xsbytes);
    int*      colbf = (int*)alloc((size_t)E * sizeof(int));
    unsigned* pairs = (unsigned*)alloc((size_t)E * sizeof(unsigned));
    float*    dinv  = (float*)alloc((size_t)NUM_NODES * sizeof(float));
    int*      rowp  = (int*)alloc((size_t)(NUM_NODES + 1) * sizeof(int));
    int*      bhist = (int*)alloc((size_t)NBUCK * sizeof(int));
    int*      bbase = (int*)alloc((size_t)NBUCK * sizeof(int));
    int*      gfill = (int*)alloc((size_t)NBUCK * sizeof(int));
    unsigned short* w1t = (unsigned short*)alloc((size_t)FEAT_DIM * HID * 2);
    unsigned short* w2t = (unsigned short*)alloc((size_t)HID * DLAT * 2);
    float* out = (float*)d_out;

    // bucketed CSR build
    hipMemsetAsync(bhist, 0, (size_t)NBUCK * sizeof(int), stream);
    hipMemsetAsync(gfill, 0, (size_t)NBUCK * sizeof(int), stream);
    bucket_hist2<<<512, 256, 0, stream>>>(usrc, idst, bhist, npair);
    bucket_scan<<<1, 512, 0, stream>>>(bhist, bbase);
    bucket_scatter2<<<(npair + CPAIR - 1) / CPAIR, 256, 0, stream>>>(usrc, idst, bbase, gfill, pairs, npair);
    csr_build<<<NBUCK, 256, 0, stream>>>(bhist, bbase, pairs, rowp, dinv, colbf);

    // weights -> bf16 transposed
    convert_weights<<<(FEAT_DIM * HID + HID * DLAT + 255) / 256, 256, 0, stream>>>(W1, W2, w1t, w2t);

    // item MLP (fused 2-layer) -> out rows NUM_USER.., xsA
    mlp_fused<<<(NUM_ITEM + 127) / 128, 512, 0, stream>>>(feats, w1t, w2t, b1, b2, dinv, out, xsA);
    pref_init<<<(NUM_USER * DLAT / 4 + 255) / 256, 256, 0, stream>>>(pref, dinv, out, xsA, NUM_USER * DLAT / 4);

    // hop 1: y1 = dinv * (A xsA); out += y1; xsB = bf16(dinv * y1)
    const int hopBlocks = (NUM_NODES * 64 + 255) / 256;
    hop_csr<<<hopBlocks, 256, 0, stream>>>(rowp, colbf, dinv, xsA, out, xsB, 0, NUM_NODES);

    // hop 2: y2 = dinv * (A xsB); out = (out + y2) / 3
    hop_csr<<<hopBlocks, 256, 0, stream>>>(rowp, colbf, dinv, xsB, out, nullptr, 1, NUM_NODES);
}

// Round 9
// 469.880 us; speedup vs baseline: 1.0388x; 1.0388x over previous
//
#include <hip/hip_runtime.h>
#include <hip/hip_fp16.h>

#define NUM_USER 100000
#define NUM_ITEM 50000
#define NUM_NODES 150000
#define FEAT_DIM 512
#define DLAT 64
#define HID 256

// bucketed CSR build
#define BSHIFT 9
#define BWIDTH 512                       // nodes per bucket
#define NBUCK 293                       // ceil(150000/512)
#define CPAIR 6144                      // pairs per bucket_scatter2 block

typedef float f32x4 __attribute__((ext_vector_type(4)));
typedef __bf16 bf16x8 __attribute__((ext_vector_type(8)));
typedef unsigned short ushort8v __attribute__((ext_vector_type(8)));

union BF8 { ushort8v u; bf16x8 b; };

__device__ inline unsigned short f2bf_rne(float f) {
    unsigned u = __float_as_uint(f);
    u += 0x7FFFu + ((u >> 16) & 1u);
    return (unsigned short)(u >> 16);
}

__device__ inline unsigned short f2h_bits(float f) {
    __half h = __float2half_rn(f);
    return *reinterpret_cast<unsigned short*>(&h);
}

__device__ inline unsigned pack2h(float a, float b) {
    __half2 h = __floats2half2_rn(a, b);
    return *reinterpret_cast<unsigned*>(&h);
}

// ---------------- pass A: bucket histogram over undirected pairs ----------------
__global__ void bucket_hist2(const int* __restrict__ usrc, const int* __restrict__ idst,
                             int* __restrict__ bhist, int npair) {
    __shared__ int h[NBUCK];
    for (int i = threadIdx.x; i < NBUCK; i += blockDim.x) h[i] = 0;
    __syncthreads();
    const int stride = gridDim.x * blockDim.x;
    for (int i = blockIdx.x * blockDim.x + threadIdx.x; i < npair; i += stride) {
        atomicAdd(&h[usrc[i] >> BSHIFT], 1);
        atomicAdd(&h[idst[i] >> BSHIFT], 1);
    }
    __syncthreads();
    for (int i = threadIdx.x; i < NBUCK; i += blockDim.x)
        if (h[i]) atomicAdd(&bhist[i], h[i]);
}

// ---------------- pass A2: exclusive scan of bucket histogram ----------------
__global__ void bucket_scan(const int* __restrict__ bhist, int* __restrict__ bbase) {
    __shared__ int s[512];
    const int t = threadIdx.x;
    const int v = (t < NBUCK) ? bhist[t] : 0;
    s[t] = v;
    __syncthreads();
    for (int off = 1; off < 512; off <<= 1) {
        int add = (t >= off) ? s[t - off] : 0;
        __syncthreads();
        s[t] += add;
        __syncthreads();
    }
    if (t < NBUCK) bbase[t] = s[t] - v;  // exclusive
}

// ---------------- pass B: LDS-staged scatter into bucket-grouped packed pairs ----------------
__launch_bounds__(256)
__global__ void bucket_scatter2(const int* __restrict__ usrc, const int* __restrict__ idst,
                                const int* __restrict__ bbase, int* __restrict__ gfill,
                                unsigned* __restrict__ pairs, int npair) {
    __shared__ unsigned stage[2 * CPAIR];   // 48 KB
    __shared__ int h[NBUCK];
    __shared__ int loff[NBUCK];
    __shared__ int gbase[NBUCK];
    __shared__ int offl[512];

    const int t = threadIdx.x;
    for (int i = t; i < NBUCK; i += 256) h[i] = 0;
    __syncthreads();

    const int p0 = blockIdx.x * CPAIR;
    const int p1 = min(p0 + CPAIR, npair);

    for (int j = p0 + t; j < p1; j += 256) {
        atomicAdd(&h[usrc[j] >> BSHIFT], 1);
        atomicAdd(&h[idst[j] >> BSHIFT], 1);
    }
    __syncthreads();

    const int v0 = h[t];
    const int v1 = (t + 256 < NBUCK) ? h[t + 256] : 0;
    offl[t] = v0; offl[t + 256] = v1;
    __syncthreads();
    for (int off = 1; off < 512; off <<= 1) {
        int a0 = (t >= off) ? offl[t - off] : 0;
        int a1 = offl[t + 256 - off];
        __syncthreads();
        offl[t] += a0;
        offl[t + 256] += a1;
        __syncthreads();
    }
    loff[t] = offl[t] - v0;
    if (t + 256 < NBUCK) loff[t + 256] = offl[t + 256] - v1;
    __syncthreads();

    for (int i = t; i < NBUCK; i += 256) {
        int c = h[i];
        gbase[i] = c ? (bbase[i] + atomicAdd(&gfill[i], c)) : 0;
    }
    __syncthreads();
    for (int i = t; i < NBUCK; i += 256) h[i] = 0;
    __syncthreads();

    for (int j = p0 + t; j < p1; j += 256) {
        int u = usrc[j], v = idst[j];
        int bu = u >> BSHIFT, bv = v >> BSHIFT;
        int pu = atomicAdd(&h[bu], 1);
        stage[loff[bu] + pu] = ((unsigned)(u & (BWIDTH - 1)) << 18) | (unsigned)v;
        int pv = atomicAdd(&h[bv], 1);
        stage[loff[bv] + pv] = ((unsigned)(v & (BWIDTH - 1)) << 18) | (unsigned)u;
    }
    __syncthreads();

    const int wv = t >> 6, ln = t & 63;
    for (int b = wv; b < NBUCK; b += 4) {
        const int len = h[b];
        const int lo  = loff[b];
        unsigned* gp = pairs + gbase[b];
        for (int k = ln; k < len; k += 64) gp[k] = stage[lo + k];
    }
}

// ---------------- pass CD: per-bucket degree count + rowptr/dinv + CSR fill ----------------
__launch_bounds__(256)
__global__ void csr_build(const int* __restrict__ bhist, const int* __restrict__ bbase,
                          const unsigned* __restrict__ pairs,
                          int* __restrict__ rowptr, float* __restrict__ dinv,
                          int* __restrict__ col) {
    __shared__ int degl[BWIDTH];
    __shared__ int offl[BWIDTH];
    const int b = blockIdx.x;
    const int t = threadIdx.x;
    const int node0 = b << BSHIFT;
    const int e0 = bbase[b];
    const int ecnt = bhist[b];

    degl[t] = 0; degl[t + 256] = 0;
    __syncthreads();
    for (int i = t; i < ecnt; i += 256)
        atomicAdd(&degl[pairs[e0 + i] >> 18], 1);
    __syncthreads();

    const int v0 = degl[t], v1 = degl[t + 256];
    offl[t] = v0; offl[t + 256] = v1;
    __syncthreads();
    for (int off = 1; off < 512; off <<= 1) {
        int a0 = (t >= off) ? offl[t - off] : 0;
        int a1 = offl[t + 256 - off];
        __syncthreads();
        offl[t] += a0;
        offl[t + 256] += a1;
        __syncthreads();
    }
    const int excl0 = offl[t] - v0;
    const int excl1 = offl[t + 256] - v1;

    const int n0 = node0 + t, n1 = node0 + t + 256;
    if (n0 < NUM_NODES) {
        rowptr[n0] = e0 + excl0;
        dinv[n0] = v0 > 0 ? rsqrtf((float)v0) : 0.0f;
    }
    if (n1 < NUM_NODES) {
        rowptr[n1] = e0 + excl1;
        dinv[n1] = v1 > 0 ? rsqrtf((float)v1) : 0.0f;
    }
    if (b == NBUCK - 1 && t == 0) rowptr[NUM_NODES] = e0 + ecnt;
    __syncthreads();

    offl[t] = excl0; offl[t + 256] = excl1;
    degl[t] = 0;     degl[t + 256] = 0;
    __syncthreads();
    for (int i = t; i < ecnt; i += 256) {
        unsigned p = pairs[e0 + i];
        int sl = p >> 18;
        int d  = (int)(p & 0x3FFFFu);
        int pos = atomicAdd(&degl[sl], 1);
        col[e0 + offl[sl] + pos] = d;
    }
}

// ---------------- weight conversion (transpose to bf16) ----------------
__global__ void convert_weights(const float* __restrict__ W1, const float* __restrict__ W2,
                                unsigned short* __restrict__ w1t, unsigned short* __restrict__ w2t) {
    int idx = blockIdx.x * blockDim.x + threadIdx.x;
    if (idx < FEAT_DIM * HID) {
        int k = idx / HID, n = idx % HID;
        w1t[(size_t)n * FEAT_DIM + k] = f2bf_rne(W1[idx]);
    } else {
        int j = idx - FEAT_DIM * HID;
        if (j < HID * DLAT) {
            int k = j / DLAT, n = j % DLAT;
            w2t[(size_t)n * HID + k] = f2bf_rne(W2[j]);
        }
    }
}

// ---------------- fused item MLP: GEMM1 (128x256, K=512) + GEMM2 (128x64, K=256) ----------------
__launch_bounds__(512, 4)
__global__ void mlp_fused(const float* __restrict__ feats,
                          const unsigned short* __restrict__ w1t,
                          const unsigned short* __restrict__ w2t,
                          const float* __restrict__ b1,
                          const float* __restrict__ b2,
                          const float* __restrict__ dinv,
                          float* __restrict__ out,
                          unsigned short* __restrict__ xs) {
    __shared__ __align__(16) unsigned char smem[65536];
    unsigned short* sA = (unsigned short*)smem;
    unsigned short* sB = (unsigned short*)(smem + 8192);
    unsigned short* sH = (unsigned short*)smem;

    const int t    = threadIdx.x;
    const int lane = t & 63;
    const int w    = t >> 6;        // 0..7
    const int wr   = w >> 2;        // 0..1
    const int wc   = w & 3;         // 0..3
    const int l15  = lane & 15;
    const int l4   = lane >> 4;
    const int item0 = blockIdx.x * 128;

    const int a_k4  = t >> 7;
    const int a_row = t & 127;
    const int a_rowg = min(item0 + a_row, NUM_ITEM - 1);
    const float* a_src = feats + (size_t)a_rowg * FEAT_DIM + a_k4 * 8;
    unsigned short* a_dst = sA + a_k4 * 1024 + a_row * 8;

    const int b_col = t & 255;
    const int b_kq  = (t >> 8) * 2;
    const unsigned short* b_src = w1t + (size_t)b_col * FEAT_DIM + b_kq * 8;
    unsigned short* b_dst = sB + b_kq * 2048 + b_col * 8;

    f32x4 acc[4][4];
    #pragma unroll
    for (int i = 0; i < 4; ++i)
        #pragma unroll
        for (int j = 0; j < 4; ++j) acc[i][j] = (f32x4)0.0f;

    for (int kk = 0; kk < 16; ++kk) {
        const int kbase = kk * 32;
        float4 f0 = *reinterpret_cast<const float4*>(a_src + kbase);
        float4 f1 = *reinterpret_cast<const float4*>(a_src + kbase + 4);
        BF8 ta;
        ta.u[0] = f2bf_rne(f0.x); ta.u[1] = f2bf_rne(f0.y);
        ta.u[2] = f2bf_rne(f0.z); ta.u[3] = f2bf_rne(f0.w);
        ta.u[4] = f2bf_rne(f1.x); ta.u[5] = f2bf_rne(f1.y);
        ta.u[6] = f2bf_rne(f1.z); ta.u[7] = f2bf_rne(f1.w);
        *reinterpret_cast<ushort8v*>(a_dst) = ta.u;
        ushort8v bv0 = *reinterpret_cast<const ushort8v*>(b_src + kbase);
        ushort8v bv1 = *reinterpret_cast<const ushort8v*>(b_src + kbase + 8);
        *reinterpret_cast<ushort8v*>(b_dst)        = bv0;
        *reinterpret_cast<ushort8v*>(b_dst + 2048) = bv1;
        __syncthreads();

        BF8 af[4];
        #pragma unroll
        for (int rf = 0; rf < 4; ++rf)
            af[rf].u = *reinterpret_cast<const ushort8v*>(sA + l4 * 1024 + (wr * 64 + rf * 16 + l15) * 8);
        #pragma unroll
        for (int cf = 0; cf < 4; ++cf) {
            BF8 bf;
            bf.u = *reinterpret_cast<const ushort8v*>(sB + l4 * 2048 + (wc * 64 + cf * 16 + l15) * 8);
            #pragma unroll
            for (int rf = 0; rf < 4; ++rf)
                acc[rf][cf] = __builtin_amdgcn_mfma_f32_16x16x32_bf16(af[rf].b, bf.b, acc[rf][cf], 0, 0, 0);
        }
        __syncthreads();
    }

    // epilogue 1: bias + leaky -> swizzled sH
    float bias[4];
    #pragma unroll
    for (int cf = 0; cf < 4; ++cf) bias[cf] = b1[wc * 64 + cf * 16 + l15];

    #pragma unroll
    for (int rf = 0; rf < 4; ++rf) {
        #pragma unroll
        for (int cf = 0; cf < 4; ++cf) {
            const int colc = wc * 64 + cf * 16 + l15;
            const int chunk = colc >> 3, within = colc & 7;
            #pragma unroll
            for (int r = 0; r < 4; ++r) {
                const int row = wr * 64 + rf * 16 + l4 * 4 + r;
                float h = acc[rf][cf][r] + bias[cf];
                h = h > 0.0f ? h : 0.01f * h;
                sH[row * 256 + ((chunk ^ (row & 7)) << 3) + within] = f2bf_rne(h);
            }
        }
    }
    __syncthreads();

    // GEMM2 in-block: rows w*16..w*16+15 (wave w), cols 0..63, K=256 from sH
    f32x4 acc2[4];
    #pragma unroll
    for (int j = 0; j < 4; ++j) acc2[j] = (f32x4)0.0f;

    const int arow = w * 16 + l15;
    const int rswz = arow & 7;
    for (int kk = 0; kk < 8; ++kk) {
        const int chunk = kk * 4 + l4;          // k = chunk*8
        BF8 ta;
        ta.u = *reinterpret_cast<const ushort8v*>(sH + arow * 256 + ((chunk ^ rswz) << 3));
        const int kbase = kk * 32 + l4 * 8;
        #pragma unroll
        for (int cf = 0; cf < 4; ++cf) {
            BF8 tb;
            tb.u = *reinterpret_cast<const ushort8v*>(w2t + (size_t)(cf * 16 + l15) * HID + kbase);
            acc2[cf] = __builtin_amdgcn_mfma_f32_16x16x32_bf16(ta.b, tb.b, acc2[cf], 0, 0, 0);
        }
    }

    #pragma unroll
    for (int cf = 0; cf < 4; ++cf) {
        const int colc = cf * 16 + l15;
        const float bias2 = b2[colc];
        #pragma unroll
        for (int r = 0; r < 4; ++r) {
            const int item = item0 + w * 16 + l4 * 4 + r;
            if (item < NUM_ITEM) {
                const int node = NUM_USER + item;
                float v = acc2[cf][r] + bias2;
                out[(size_t)node * DLAT + colc] = v;
                xs [(size_t)node * DLAT + colc] = f2h_bits(v * dinv[node]);   // fp16 state
            }
        }
    }
}

// ---------------- user init: out = pref, xs = f16(pref * dinv) ----------------
__global__ void pref_init(const float* __restrict__ pref, const float* __restrict__ dinv,
                          float* __restrict__ out, unsigned short* __restrict__ xs, int n4) {
    int i = blockIdx.x * blockDim.x + threadIdx.x;
    if (i < n4) {
        float4 v = reinterpret_cast<const float4*>(pref)[i];
        float di = dinv[i >> 4];
        reinterpret_cast<float4*>(out)[i] = v;
        uint2 p;
        p.x = pack2h(v.x * di, v.y * di);
        p.y = pack2h(v.z * di, v.w * di);
        *reinterpret_cast<uint2*>(xs + (size_t)i * 4) = p;
    }
}

// ---------------- CSR gather hop (f16 state, packed-half accumulate) ----------------
// lane = (g, r16): g = lane>>4 picks neighbor mod 4, r16 = lane&15 handles dims 4*r16..+3.
// One uint2 load covers 4 dims; accumulate with __hadd2 (v_pk_add_f16): 2 VALU per row-lane.
__launch_bounds__(256)
__global__ void hop_csr(const int* __restrict__ rowptr, const int* __restrict__ col,
                        const float* __restrict__ dinv, const unsigned short* __restrict__ xs,
                        float* __restrict__ out, unsigned short* __restrict__ xs_next,
                        int is_final, int n) {
    const int wave = (blockIdx.x * blockDim.x + threadIdx.x) >> 6;
    const int lane = threadIdx.x & 63;
    if (wave >= n) return;
    const int r0  = rowptr[wave];
    const int r1  = rowptr[wave + 1];
    const int g   = lane >> 4;
    const int r16 = lane & 15;
    const char* xsb = (const char*)xs + r16 * 8;

    __half2 h01 = __floats2half2_rn(0.0f, 0.0f);
    __half2 h23 = h01;

    for (int base = r0; base < r1; base += 64) {
        int rem = r1 - base; if (rem > 64) rem = 64;
        int cvec = (lane < rem) ? col[base + lane] : 0;
        int j = 0;
        for (; j + 16 <= rem; j += 16) {
            int c0 = __shfl(cvec, j + g);
            int c1 = __shfl(cvec, j + 4 + g);
            int c2 = __shfl(cvec, j + 8 + g);
            int c3 = __shfl(cvec, j + 12 + g);
            uint2 v0 = *reinterpret_cast<const uint2*>(xsb + (size_t)c0 * 128);
            uint2 v1 = *reinterpret_cast<const uint2*>(xsb + (size_t)c1 * 128);
            uint2 v2 = *reinterpret_cast<const uint2*>(xsb + (size_t)c2 * 128);
            uint2 v3 = *reinterpret_cast<const uint2*>(xsb + (size_t)c3 * 128);
            h01 = __hadd2(h01, *reinterpret_cast<const __half2*>(&v0.x));
            h23 = __hadd2(h23, *reinterpret_cast<const __half2*>(&v0.y));
            h01 = __hadd2(h01, *reinterpret_cast<const __half2*>(&v1.x));
            h23 = __hadd2(h23, *reinterpret_cast<const __half2*>(&v1.y));
            h01 = __hadd2(h01, *reinterpret_cast<const __half2*>(&v2.x));
            h23 = __hadd2(h23, *reinterpret_cast<const __half2*>(&v2.y));
            h01 = __hadd2(h01, *reinterpret_cast<const __half2*>(&v3.x));
            h23 = __hadd2(h23, *reinterpret_cast<const __half2*>(&v3.y));
        }
        for (; j + 4 <= rem; j += 4) {
            int c = __shfl(cvec, j + g);
            uint2 v = *reinterpret_cast<const uint2*>(xsb + (size_t)c * 128);
            h01 = __hadd2(h01, *reinterpret_cast<const __half2*>(&v.x));
            h23 = __hadd2(h23, *reinterpret_cast<const __half2*>(&v.y));
        }
        int tail = rem - j;  // 0..3
        if (tail > 0) {
            int jj = j + g;
            int cj = __shfl(cvec, jj < rem ? jj : (rem - 1));
            if (jj < rem) {
                uint2 v = *reinterpret_cast<const uint2*>(xsb + (size_t)cj * 128);
                h01 = __hadd2(h01, *reinterpret_cast<const __half2*>(&v.x));
                h23 = __hadd2(h23, *reinterpret_cast<const __half2*>(&v.y));
            }
        }
    }

    // to f32, reduce across the 4 groups (lanes with same r16)
    float s0 = __low2float(h01), s1 = __high2float(h01);
    float s2 = __low2float(h23), s3 = __high2float(h23);
    s0 += __shfl_xor(s0, 16); s0 += __shfl_xor(s0, 32);
    s1 += __shfl_xor(s1, 16); s1 += __shfl_xor(s1, 32);
    s2 += __shfl_xor(s2, 16); s2 += __shfl_xor(s2, 32);
    s3 += __shfl_xor(s3, 16); s3 += __shfl_xor(s3, 32);

    if (g == 0) {
        float di = dinv[wave];
        float y0 = di * s0, y1 = di * s1, y2 = di * s2, y3 = di * s3;
        size_t o = (size_t)wave * DLAT + 4 * r16;
        float4 prev = *reinterpret_cast<const float4*>(out + o);
        if (is_final) {
            float4 wv;
            wv.x = (prev.x + y0) * (1.0f / 3.0f);
            wv.y = (prev.y + y1) * (1.0f / 3.0f);
            wv.z = (prev.z + y2) * (1.0f / 3.0f);
            wv.w = (prev.w + y3) * (1.0f / 3.0f);
            *reinterpret_cast<float4*>(out + o) = wv;
        } else {
            float4 wv;
            wv.x = prev.x + y0;
            wv.y = prev.y + y1;
            wv.z = prev.z + y2;
            wv.w = prev.w + y3;
            *reinterpret_cast<float4*>(out + o) = wv;
            uint2 p;
            p.x = pack2h(di * y0, di * y1);
            p.y = pack2h(di * y2, di * y3);
            *reinterpret_cast<uint2*>(xs_next + o) = p;
        }
    }
}

extern "C" void kernel_launch(void* const* d_in, const int* in_sizes, int n_in,
                              void* d_out, int out_size, void* d_ws, size_t ws_size,
                              hipStream_t stream) {
    const float* feats = (const float*)d_in[0];
    const int*   eidx  = (const int*)d_in[1];
    const float* pref  = (const float*)d_in[2];
    const float* W1    = (const float*)d_in[3];
    const float* b1    = (const float*)d_in[4];
    const float* W2    = (const float*)d_in[5];
    const float* b2    = (const float*)d_in[6];

    const int E = in_sizes[1] / 2;       // directed edges
    const int npair = E / 2;             // undirected pairs; row0 = [src_u | dst_i]
    const int* usrc = eidx;
    const int* idst = eidx + npair;

    char* ws = (char*)d_ws;
    size_t off = 0;
    auto alloc = [&](size_t bytes) -> void* {
        void* p = ws + off;
        off += (bytes + 255) & ~(size_t)255;
        return p;
    };
    const size_t xsbytes = (size_t)NUM_NODES * DLAT * sizeof(unsigned short);
    unsigned short* xsA = (unsigned short*)alloc(xsbytes);
    unsigned short* xsB = (unsigned short*)alloc(xsbytes);
    int*      colbf = (int*)alloc((size_t)E * sizeof(int));
    unsigned* pairs = (unsigned*)alloc((size_t)E * sizeof(unsigned));
    float*    dinv  = (float*)alloc((size_t)NUM_NODES * sizeof(float));
    int*      rowp  = (int*)alloc((size_t)(NUM_NODES + 1) * sizeof(int));
    int*      bhist = (int*)alloc((size_t)NBUCK * sizeof(int));
    int*      bbase = (int*)alloc((size_t)NBUCK * sizeof(int));
    int*      gfill = (int*)alloc((size_t)NBUCK * sizeof(int));
    unsigned short* w1t = (unsigned short*)alloc((size_t)FEAT_DIM * HID * 2);
    unsigned short* w2t = (unsigned short*)alloc((size_t)HID * DLAT * 2);
    float* out = (float*)d_out;

    // bucketed CSR build
    hipMemsetAsync(bhist, 0, (size_t)NBUCK * sizeof(int), stream);
    hipMemsetAsync(gfill, 0, (size_t)NBUCK * sizeof(int), stream);
    bucket_hist2<<<512, 256, 0, stream>>>(usrc, idst, bhist, npair);
    bucket_scan<<<1, 512, 0, stream>>>(bhist, bbase);
    bucket_scatter2<<<(npair + CPAIR - 1) / CPAIR, 256, 0, stream>>>(usrc, idst, bbase, gfill, pairs, npair);
    csr_build<<<NBUCK, 256, 0, stream>>>(bhist, bbase, pairs, rowp, dinv, colbf);

    // weights -> bf16 transposed
    convert_weights<<<(FEAT_DIM * HID + HID * DLAT + 255) / 256, 256, 0, stream>>>(W1, W2, w1t, w2t);

    // item MLP (fused 2-layer) -> out rows NUM_USER.., xsA (f16)
    mlp_fused<<<(NUM_ITEM + 127) / 128, 512, 0, stream>>>(feats, w1t, w2t, b1, b2, dinv, out, xsA);
    pref_init<<<(NUM_USER * DLAT / 4 + 255) / 256, 256, 0, stream>>>(pref, dinv, out, xsA, NUM_USER * DLAT / 4);

    // hop 1: y1 = dinv * (A xsA); out += y1; xsB = f16(dinv * y1)
    const int hopBlocks = (NUM_NODES * 64 + 255) / 256;
    hop_csr<<<hopBlocks, 256, 0, stream>>>(rowp, colbf, dinv, xsA, out, xsB, 0, NUM_NODES);

    // hop 2: y2 = dinv * (A xsB); out = (out + y2) / 3
    hop_csr<<<hopBlocks, 256, 0, stream>>>(rowp, colbf, dinv, xsB, out, nullptr, 1, NUM_NODES);
}